// Round 1
// baseline (593.318 us; speedup 1.0000x reference)
//
#include <hip/hip_runtime.h>
#include <cstddef>

// Problem constants
static constexpr int M_ROWS  = 32768;   // B*T = 64*512
static constexpr int D_INK   = 1024;
static constexpr int D_HID   = 512;
static constexpr int D_CODE_ = 256;
static constexpr int N_CODES_= 128;

// ---------------------------------------------------------------------------
// prep: transpose codebook [128,256] -> cbT [256,128], compute per-code norms,
// zero the loss accumulators (must happen every call: harness doesn't re-poison)
// ---------------------------------------------------------------------------
__global__ __launch_bounds__(256)
void prep_cb_kernel(const float* __restrict__ cb, float* __restrict__ cbT,
                    float* __restrict__ cbnorm, float* __restrict__ accum)
{
    const int j = blockIdx.x;      // code index 0..127
    const int t = threadIdx.x;     // dim index 0..255
    const float v = cb[j * D_CODE_ + t];
    cbT[t * N_CODES_ + j] = v;

    __shared__ float sr[256];
    sr[t] = v * v;
    __syncthreads();
    for (int s = 128; s >= 1; s >>= 1) {
        if (t < s) sr[t] += sr[t + s];
        __syncthreads();
    }
    if (t == 0) cbnorm[j] = sr[0];
    if (j == 0 && t < 2) accum[t] = 0.0f;
}

// ---------------------------------------------------------------------------
// SGEMM: C[m,n] = (relu?)(A[m,:K] @ B[:K,n] + bias[n])
// 128x128 tile, BK=8, 256 threads, 8x8 per thread. A,B,C row-major.
// grid.x = M/128 (fast, for L2 reuse of the B column panel), grid.y = N/128.
// ---------------------------------------------------------------------------
template<bool RELU>
__global__ __launch_bounds__(256)
void sgemm_bias_kernel(const float* __restrict__ A, const float* __restrict__ B,
                       const float* __restrict__ bias, float* __restrict__ C,
                       int Kdim, int Ndim)
{
    __shared__ float As[8][128];   // transposed: As[k][m]
    __shared__ float Bs[8][128];   // Bs[k][n]

    const int tid = threadIdx.x;
    const int m0 = blockIdx.x * 128;
    const int n0 = blockIdx.y * 128;

    const int r0 = (tid >> 4) * 8;     // row offset in tile
    const int c0 = (tid & 15) * 8;     // col offset in tile

    const int a_row = tid >> 1;        // 0..127
    const int a_col = (tid & 1) * 4;   // 0 or 4
    const int b_row = tid >> 5;        // 0..7
    const int b_col = (tid & 31) * 4;  // 0..124

    const float* Ap = A + (size_t)(m0 + a_row) * Kdim + a_col;
    const float* Bp = B + (size_t)b_row * Ndim + n0 + b_col;

    float acc[8][8];
    #pragma unroll
    for (int i = 0; i < 8; ++i)
        #pragma unroll
        for (int j = 0; j < 8; ++j) acc[i][j] = 0.0f;

    for (int k0 = 0; k0 < Kdim; k0 += 8) {
        const float4 av = *(const float4*)(Ap + k0);
        const float4 bv = *(const float4*)(Bp + (size_t)k0 * Ndim);
        __syncthreads();               // previous iter's LDS reads done
        As[a_col + 0][a_row] = av.x;
        As[a_col + 1][a_row] = av.y;
        As[a_col + 2][a_row] = av.z;
        As[a_col + 3][a_row] = av.w;
        *(float4*)(&Bs[b_row][b_col]) = bv;
        __syncthreads();               // LDS writes visible
        #pragma unroll
        for (int kk = 0; kk < 8; ++kk) {
            float a[8], b[8];
            *(float4*)(&a[0]) = *(const float4*)(&As[kk][r0]);
            *(float4*)(&a[4]) = *(const float4*)(&As[kk][r0 + 4]);
            *(float4*)(&b[0]) = *(const float4*)(&Bs[kk][c0]);
            *(float4*)(&b[4]) = *(const float4*)(&Bs[kk][c0 + 4]);
            #pragma unroll
            for (int i = 0; i < 8; ++i)
                #pragma unroll
                for (int j = 0; j < 8; ++j)
                    acc[i][j] = fmaf(a[i], b[j], acc[i][j]);
        }
    }

    #pragma unroll
    for (int i = 0; i < 8; ++i) {
        float* Crow = C + (size_t)(m0 + r0 + i) * Ndim + n0;
        #pragma unroll
        for (int j = 0; j < 8; j += 4) {
            float4 v;
            v.x = acc[i][j + 0] + bias[n0 + c0 + j + 0];
            v.y = acc[i][j + 1] + bias[n0 + c0 + j + 1];
            v.z = acc[i][j + 2] + bias[n0 + c0 + j + 2];
            v.w = acc[i][j + 3] + bias[n0 + c0 + j + 3];
            if (RELU) {
                v.x = fmaxf(v.x, 0.0f); v.y = fmaxf(v.y, 0.0f);
                v.z = fmaxf(v.z, 0.0f); v.w = fmaxf(v.w, 0.0f);
            }
            *(float4*)(Crow + c0 + j) = v;
        }
    }
}

// ---------------------------------------------------------------------------
// dist+argmin: dots[m,j] = enc[m,:] . cb[j,:] via GEMM (BN=128 covers ALL codes)
// epilogue: per-row argmin_j (cbnorm[j] - 2*dots[m,j])  (rownorm is constant
// per row -> doesn't affect argmin). Loss pieces:
//   Sum_rows d2_min = Sum(enc^2)  [accumulated during A-tile loads, each
//   element loaded exactly once since there is a single column block]
//                   + Sum_rows min_j(cbnorm_j - 2 dot_j)
// Writes argmin index (as float) to outIdx, atomicAdds the two partial sums.
// ---------------------------------------------------------------------------
__global__ __launch_bounds__(256)
void dist_argmin_kernel(const float* __restrict__ E, const float* __restrict__ CbT,
                        const float* __restrict__ cbnorm,
                        float* __restrict__ outIdx, float* __restrict__ accum)
{
    __shared__ float As[8][128];
    __shared__ float Bs[8][128];
    __shared__ float sCbn[128];
    __shared__ float sMin[128][17];   // +1 pad
    __shared__ int   sIdx[128][17];
    __shared__ float sRed[256];

    const int tid = threadIdx.x;
    const int m0 = blockIdx.x * 128;
    const int r0 = (tid >> 4) * 8;
    const int tc = tid & 15;
    const int c0 = tc * 8;

    if (tid < 128) sCbn[tid] = cbnorm[tid];

    const int a_row = tid >> 1;
    const int a_col = (tid & 1) * 4;
    const int b_row = tid >> 5;
    const int b_col = (tid & 31) * 4;

    const float* Ap = E + (size_t)(m0 + a_row) * D_CODE_ + a_col;
    const float* Bp = CbT + (size_t)b_row * N_CODES_ + b_col;

    float acc[8][8];
    #pragma unroll
    for (int i = 0; i < 8; ++i)
        #pragma unroll
        for (int j = 0; j < 8; ++j) acc[i][j] = 0.0f;

    float sumsq = 0.0f;

    for (int k0 = 0; k0 < D_CODE_; k0 += 8) {
        const float4 av = *(const float4*)(Ap + k0);
        const float4 bv = *(const float4*)(Bp + (size_t)k0 * N_CODES_);
        sumsq = fmaf(av.x, av.x, sumsq);
        sumsq = fmaf(av.y, av.y, sumsq);
        sumsq = fmaf(av.z, av.z, sumsq);
        sumsq = fmaf(av.w, av.w, sumsq);
        __syncthreads();
        As[a_col + 0][a_row] = av.x;
        As[a_col + 1][a_row] = av.y;
        As[a_col + 2][a_row] = av.z;
        As[a_col + 3][a_row] = av.w;
        *(float4*)(&Bs[b_row][b_col]) = bv;
        __syncthreads();
        #pragma unroll
        for (int kk = 0; kk < 8; ++kk) {
            float a[8], b[8];
            *(float4*)(&a[0]) = *(const float4*)(&As[kk][r0]);
            *(float4*)(&a[4]) = *(const float4*)(&As[kk][r0 + 4]);
            *(float4*)(&b[0]) = *(const float4*)(&Bs[kk][c0]);
            *(float4*)(&b[4]) = *(const float4*)(&Bs[kk][c0 + 4]);
            #pragma unroll
            for (int i = 0; i < 8; ++i)
                #pragma unroll
                for (int j = 0; j < 8; ++j)
                    acc[i][j] = fmaf(a[i], b[j], acc[i][j]);
        }
    }

    // per-thread argmin over its 8 codes (codes c0..c0+7, ascending -> first-min)
    #pragma unroll
    for (int i = 0; i < 8; ++i) {
        float best = 3.4e38f;
        int bj = 0;
        #pragma unroll
        for (int j = 0; j < 8; ++j) {
            const float v = fmaf(-2.0f, acc[i][j], sCbn[c0 + j]);
            if (v < best) { best = v; bj = c0 + j; }
        }
        sMin[r0 + i][tc] = best;
        sIdx[r0 + i][tc] = bj;
    }
    __syncthreads();

    // per-row final argmin across the 16 column-thread partials (tc ascending
    // preserves numpy first-occurrence tie-break)
    float rowVal = 0.0f;
    if (tid < 128) {
        float best = sMin[tid][0];
        int bj = sIdx[tid][0];
        #pragma unroll
        for (int t2 = 1; t2 < 16; ++t2) {
            const float v = sMin[tid][t2];
            if (v < best) { best = v; bj = sIdx[tid][t2]; }
        }
        outIdx[m0 + tid] = (float)bj;
        rowVal = best;
    }

    // block-reduce rowVal (threads <128) then sumsq (all threads)
    sRed[tid] = (tid < 128) ? rowVal : 0.0f;
    __syncthreads();
    for (int s = 128; s >= 1; s >>= 1) {
        if (tid < s) sRed[tid] += sRed[tid + s];
        __syncthreads();
    }
    const float minSum = sRed[0];
    __syncthreads();
    sRed[tid] = sumsq;
    __syncthreads();
    for (int s = 128; s >= 1; s >>= 1) {
        if (tid < s) sRed[tid] += sRed[tid + s];
        __syncthreads();
    }
    if (tid == 0) {
        atomicAdd(&accum[0], minSum);
        atomicAdd(&accum[1], sRed[0]);
    }
}

// ---------------------------------------------------------------------------
__global__ void finalize_kernel(const float* __restrict__ accum, float* __restrict__ out)
{
    const float inv = 1.0f / (32768.0f * 256.0f);
    const float loss = (accum[0] + accum[1]) * inv;   // == commitment == codebook
    out[32768] = loss;
    out[32769] = loss;
    out[32770] = 1.25f * loss;
}

// ---------------------------------------------------------------------------
extern "C" void kernel_launch(void* const* d_in, const int* in_sizes, int n_in,
                              void* d_out, int out_size, void* d_ws, size_t ws_size,
                              hipStream_t stream)
{
    (void)in_sizes; (void)n_in; (void)out_size; (void)ws_size;

    const float* x  = (const float*)d_in[0];  // [32768,1024]
    const float* W1 = (const float*)d_in[1];  // [1024,512]
    const float* b1 = (const float*)d_in[2];  // [512]
    const float* W2 = (const float*)d_in[3];  // [512,256]
    const float* b2 = (const float*)d_in[4];  // [256]
    const float* cb = (const float*)d_in[5];  // [128,256]
    // d_in[6], d_in[7] (Wd, bd) are dead code in the reference.

    float* out = (float*)d_out;

    // workspace layout (bytes): h 64MB | encoded 32MB | cbT 128KB | cbnorm 512B | accum
    char* ws = (char*)d_ws;
    float* h     = (float*)(ws);
    float* enc   = (float*)(ws + (size_t)67108864);
    float* cbT   = (float*)(ws + (size_t)67108864 + 33554432);
    float* cbn   = (float*)(ws + (size_t)67108864 + 33554432 + 131072);
    float* accum = (float*)(ws + (size_t)67108864 + 33554432 + 131072 + 512);

    prep_cb_kernel<<<N_CODES_, 256, 0, stream>>>(cb, cbT, cbn, accum);
    // h = relu(x @ W1 + b1) : M=32768, K=1024, N=512
    sgemm_bias_kernel<true ><<<dim3(M_ROWS / 128, D_HID  / 128), 256, 0, stream>>>(x, W1, b1, h, D_INK, D_HID);
    // enc = h @ W2 + b2     : M=32768, K=512,  N=256
    sgemm_bias_kernel<false><<<dim3(M_ROWS / 128, D_CODE_ / 128), 256, 0, stream>>>(h, W2, b2, enc, D_HID, D_CODE_);
    // distances + argmin + loss partials
    dist_argmin_kernel<<<M_ROWS / 128, 256, 0, stream>>>(enc, cbT, cbn, out, accum);
    finalize_kernel<<<1, 1, 0, stream>>>(accum, out);
}

// Round 2
// 380.690 us; speedup vs baseline: 1.5585x; 1.5585x over previous
//
#include <hip/hip_runtime.h>
#include <cstddef>
#include <cstdint>

// Problem constants
static constexpr int M_ROWS  = 32768;   // B*T = 64*512
static constexpr int D_INK   = 1024;
static constexpr int D_HID   = 512;
static constexpr int D_CODE_ = 256;
static constexpr int N_CODES_= 128;

static constexpr float TAU_GAP = 0.125f;   // ambiguity threshold for exact-recompute

using bf16x8 = __attribute__((ext_vector_type(8))) __bf16;
using f32x4  = __attribute__((ext_vector_type(4))) float;

// ---------------------------------------------------------------------------
// prep: transpose codebook [128,256] -> cbT [256,128], per-code norms,
// zero loss accumulators + ambiguous-row counter (every call).
// ---------------------------------------------------------------------------
__global__ __launch_bounds__(256)
void prep_cb_kernel(const float* __restrict__ cb, float* __restrict__ cbT,
                    float* __restrict__ cbnorm, float* __restrict__ accum,
                    int* __restrict__ cnt)
{
    const int j = blockIdx.x;      // code index 0..127
    const int t = threadIdx.x;     // dim index 0..255
    const float v = cb[j * D_CODE_ + t];
    cbT[t * N_CODES_ + j] = v;

    __shared__ float sr[256];
    sr[t] = v * v;
    __syncthreads();
    for (int s = 128; s >= 1; s >>= 1) {
        if (t < s) sr[t] += sr[t + s];
        __syncthreads();
    }
    if (t == 0) cbnorm[j] = sr[0];
    if (j == 0 && t < 2) accum[t] = 0.0f;
    if (j == 0 && t == 2) *cnt = 0;
}

// ---------------------------------------------------------------------------
// splitT: W [K][N] fp32 -> WT_hi/WT_lo [N][K] bf16 (hi = rne(bf16), lo = rest)
// grid (K, N/256), 256 threads; coalesced reads, scattered 2B writes (L2-absorbed)
// ---------------------------------------------------------------------------
__global__ __launch_bounds__(256)
void splitT_kernel(const float* __restrict__ W, __bf16* __restrict__ Thi,
                   __bf16* __restrict__ Tlo, int Kd, int Nd)
{
    const int k = blockIdx.x;
    const int n = blockIdx.y * 256 + threadIdx.x;
    const float v = W[(size_t)k * Nd + n];
    const __bf16 hb = (__bf16)v;
    const __bf16 lb = (__bf16)(v - (float)hb);
    Thi[(size_t)n * Kd + k] = hb;
    Tlo[(size_t)n * Kd + k] = lb;
}

// ---------------------------------------------------------------------------
// MFMA GEMM with bf16 hi/lo 3-product split (~fp32 accuracy).
//   C[M,N] = act(A[M,K] @ B[K,N] + bias)
// A: fp32 [M][K] (A_BF16=false) or bf16 pair [M][K] (A_BF16=true)
// B: pre-split transposed bf16 pair [N][K]
// OUT_BF16RELU: relu + write bf16 hi/lo pair; else write fp32.
// 128x128 tile, BK=32, 4 waves (2x2 of 64x64), mfma_f32_16x16x32_bf16.
// LDS frag-linear: frag f=(kg*128+idx) at byte f*16 -> conflict-free r/w.
// ---------------------------------------------------------------------------
template<bool A_BF16, bool OUT_BF16RELU>
__global__ __launch_bounds__(256)
void mfma_gemm_kernel(const float* __restrict__ Af32,
                      const __bf16* __restrict__ Ahi, const __bf16* __restrict__ Alo,
                      const __bf16* __restrict__ BThi, const __bf16* __restrict__ BTlo,
                      const float* __restrict__ bias,
                      float* __restrict__ Cf32,
                      __bf16* __restrict__ Chi, __bf16* __restrict__ Clo,
                      int Kd, int Nd)
{
    __shared__ __align__(16) __bf16 sAh[4096];
    __shared__ __align__(16) __bf16 sAl[4096];
    __shared__ __align__(16) __bf16 sBh[4096];
    __shared__ __align__(16) __bf16 sBl[4096];

    const int tid  = threadIdx.x;
    const int lane = tid & 63;
    const int w    = tid >> 6;
    const int wm   = w >> 1, wn = w & 1;
    const int m0 = blockIdx.x * 128, n0 = blockIdx.y * 128;

    f32x4 acc[4][4];
    #pragma unroll
    for (int i = 0; i < 4; ++i)
        #pragma unroll
        for (int j = 0; j < 4; ++j)
            acc[i][j] = (f32x4){0.f, 0.f, 0.f, 0.f};

    const int kq = lane >> 4;      // 0..3 (k-group within MFMA)
    const int lm = lane & 15;      // row/col within fragment

    for (int k0 = 0; k0 < Kd; k0 += 32) {
        __syncthreads();           // previous iter's LDS reads done
        // ---- stage A (2 frags/thread) + B (2 frags/thread) ----
        #pragma unroll
        for (int s = 0; s < 2; ++s) {
            const int f  = s * 256 + tid;       // 0..511
            const int mi = f & 127;
            const int kg = f >> 7;              // 0..3
            // A
            if (A_BF16) {
                const size_t off = (size_t)(m0 + mi) * Kd + k0 + kg * 8;
                *reinterpret_cast<bf16x8*>(sAh + f * 8) =
                    *reinterpret_cast<const bf16x8*>(Ahi + off);
                *reinterpret_cast<bf16x8*>(sAl + f * 8) =
                    *reinterpret_cast<const bf16x8*>(Alo + off);
            } else {
                const float* sp = Af32 + (size_t)(m0 + mi) * Kd + k0 + kg * 8;
                float vv[8];
                *(float4*)&vv[0] = *(const float4*)(sp);
                *(float4*)&vv[4] = *(const float4*)(sp + 4);
                bf16x8 hf, lf;
                #pragma unroll
                for (int jj = 0; jj < 8; ++jj) {
                    const __bf16 hb = (__bf16)vv[jj];
                    hf[jj] = hb;
                    lf[jj] = (__bf16)(vv[jj] - (float)hb);
                }
                *reinterpret_cast<bf16x8*>(sAh + f * 8) = hf;
                *reinterpret_cast<bf16x8*>(sAl + f * 8) = lf;
            }
            // B (always pre-split bf16, [N][K])
            {
                const size_t off = (size_t)(n0 + mi) * Kd + k0 + kg * 8;
                *reinterpret_cast<bf16x8*>(sBh + f * 8) =
                    *reinterpret_cast<const bf16x8*>(BThi + off);
                *reinterpret_cast<bf16x8*>(sBl + f * 8) =
                    *reinterpret_cast<const bf16x8*>(BTlo + off);
            }
        }
        __syncthreads();           // staged data visible

        // ---- compute ----
        bf16x8 ah[4], al[4];
        #pragma unroll
        for (int fm = 0; fm < 4; ++fm) {
            const int fA = kq * 128 + wm * 64 + fm * 16 + lm;
            ah[fm] = *reinterpret_cast<const bf16x8*>(sAh + fA * 8);
            al[fm] = *reinterpret_cast<const bf16x8*>(sAl + fA * 8);
        }
        #pragma unroll
        for (int fn = 0; fn < 4; ++fn) {
            const int fB = kq * 128 + wn * 64 + fn * 16 + lm;
            const bf16x8 bh = *reinterpret_cast<const bf16x8*>(sBh + fB * 8);
            const bf16x8 bl = *reinterpret_cast<const bf16x8*>(sBl + fB * 8);
            #pragma unroll
            for (int fm = 0; fm < 4; ++fm) {
                acc[fm][fn] = __builtin_amdgcn_mfma_f32_16x16x32_bf16(ah[fm], bh, acc[fm][fn], 0, 0, 0);
                acc[fm][fn] = __builtin_amdgcn_mfma_f32_16x16x32_bf16(al[fm], bh, acc[fm][fn], 0, 0, 0);
                acc[fm][fn] = __builtin_amdgcn_mfma_f32_16x16x32_bf16(ah[fm], bl, acc[fm][fn], 0, 0, 0);
            }
        }
    }

    // ---- epilogue: C/D frag mapping col=lane&15, row=(lane>>4)*4+reg ----
    const int kq4 = kq * 4;
    #pragma unroll
    for (int fn = 0; fn < 4; ++fn) {
        const int col = n0 + wn * 64 + fn * 16 + lm;
        const float bv = bias[col];
        #pragma unroll
        for (int fm = 0; fm < 4; ++fm) {
            #pragma unroll
            for (int r = 0; r < 4; ++r) {
                const int row = m0 + wm * 64 + fm * 16 + kq4 + r;
                float v = acc[fm][fn][r] + bv;
                if (OUT_BF16RELU) {
                    v = fmaxf(v, 0.0f);
                    const __bf16 hb = (__bf16)v;
                    Chi[(size_t)row * Nd + col] = hb;
                    Clo[(size_t)row * Nd + col] = (__bf16)(v - (float)hb);
                } else {
                    Cf32[(size_t)row * Nd + col] = v;
                }
            }
        }
    }
}

// ---------------------------------------------------------------------------
// dist+argmin (fp32): dots = enc @ cbT, argmin_j(cbnorm_j - 2*dot_j) per row.
// Also: second-best gap -> flag ambiguous rows for exact recompute; loss sums.
// ---------------------------------------------------------------------------
__global__ __launch_bounds__(256)
void dist_argmin_kernel(const float* __restrict__ E, const float* __restrict__ CbT,
                        const float* __restrict__ cbnorm,
                        float* __restrict__ outIdx, float* __restrict__ accum,
                        int* __restrict__ cnt, int* __restrict__ list)
{
    __shared__ float As[8][128];
    __shared__ float Bs[8][128];
    __shared__ float sCbn[128];
    __shared__ float sMin[128][17];
    __shared__ float sMin2[128][17];
    __shared__ int   sIdx[128][17];
    __shared__ float sRed[256];

    const int tid = threadIdx.x;
    const int m0 = blockIdx.x * 128;
    const int r0 = (tid >> 4) * 8;
    const int tc = tid & 15;
    const int c0 = tc * 8;

    if (tid < 128) sCbn[tid] = cbnorm[tid];

    const int a_row = tid >> 1;
    const int a_col = (tid & 1) * 4;
    const int b_row = tid >> 5;
    const int b_col = (tid & 31) * 4;

    const float* Ap = E + (size_t)(m0 + a_row) * D_CODE_ + a_col;
    const float* Bp = CbT + (size_t)b_row * N_CODES_ + b_col;

    float acc[8][8];
    #pragma unroll
    for (int i = 0; i < 8; ++i)
        #pragma unroll
        for (int j = 0; j < 8; ++j) acc[i][j] = 0.0f;

    float sumsq = 0.0f;

    for (int k0 = 0; k0 < D_CODE_; k0 += 8) {
        const float4 av = *(const float4*)(Ap + k0);
        const float4 bv = *(const float4*)(Bp + (size_t)k0 * N_CODES_);
        sumsq = fmaf(av.x, av.x, sumsq);
        sumsq = fmaf(av.y, av.y, sumsq);
        sumsq = fmaf(av.z, av.z, sumsq);
        sumsq = fmaf(av.w, av.w, sumsq);
        __syncthreads();
        As[a_col + 0][a_row] = av.x;
        As[a_col + 1][a_row] = av.y;
        As[a_col + 2][a_row] = av.z;
        As[a_col + 3][a_row] = av.w;
        *(float4*)(&Bs[b_row][b_col]) = bv;
        __syncthreads();
        #pragma unroll
        for (int kk = 0; kk < 8; ++kk) {
            float a[8], b[8];
            *(float4*)(&a[0]) = *(const float4*)(&As[kk][r0]);
            *(float4*)(&a[4]) = *(const float4*)(&As[kk][r0 + 4]);
            *(float4*)(&b[0]) = *(const float4*)(&Bs[kk][c0]);
            *(float4*)(&b[4]) = *(const float4*)(&Bs[kk][c0 + 4]);
            #pragma unroll
            for (int i = 0; i < 8; ++i)
                #pragma unroll
                for (int j = 0; j < 8; ++j)
                    acc[i][j] = fmaf(a[i], b[j], acc[i][j]);
        }
    }

    // per-thread best + second-best over its 8 codes (ascending -> first-min)
    #pragma unroll
    for (int i = 0; i < 8; ++i) {
        float b1 = 3.4e38f, b2 = 3.4e38f;
        int bj = 0;
        #pragma unroll
        for (int j = 0; j < 8; ++j) {
            const float v = fmaf(-2.0f, acc[i][j], sCbn[c0 + j]);
            if (v < b1) { b2 = b1; b1 = v; bj = c0 + j; }
            else if (v < b2) b2 = v;
        }
        sMin[r0 + i][tc]  = b1;
        sMin2[r0 + i][tc] = b2;
        sIdx[r0 + i][tc]  = bj;
    }
    __syncthreads();

    float rowVal = 0.0f;
    if (tid < 128) {
        float B1 = 3.4e38f, B2 = 3.4e38f;
        int I1 = 0;
        #pragma unroll
        for (int t2 = 0; t2 < 16; ++t2) {
            const float p1 = sMin[tid][t2];
            const float p2 = sMin2[tid][t2];
            if (p1 < B1) { B2 = fminf(B1, p2); B1 = p1; I1 = sIdx[tid][t2]; }
            else         { B2 = fminf(B2, p1); }
        }
        outIdx[m0 + tid] = (float)I1;
        rowVal = B1;
        if (B2 - B1 < TAU_GAP) {              // ambiguous under bf16x3 jitter
            const int pos = atomicAdd(cnt, 1);
            list[pos] = m0 + tid;
        }
    }

    sRed[tid] = (tid < 128) ? rowVal : 0.0f;
    __syncthreads();
    for (int s = 128; s >= 1; s >>= 1) {
        if (tid < s) sRed[tid] += sRed[tid + s];
        __syncthreads();
    }
    const float minSum = sRed[0];
    __syncthreads();
    sRed[tid] = sumsq;
    __syncthreads();
    for (int s = 128; s >= 1; s >>= 1) {
        if (tid < s) sRed[tid] += sRed[tid + s];
        __syncthreads();
    }
    if (tid == 0) {
        atomicAdd(&accum[0], minSum);
        atomicAdd(&accum[1], sRed[0]);
    }
}

// ---------------------------------------------------------------------------
// fixup: exact fp32 recompute of flagged (near-tie) rows; overwrite index.
// ---------------------------------------------------------------------------
__global__ __launch_bounds__(256)
void fixup_kernel(const float* __restrict__ x, const float* __restrict__ W1,
                  const float* __restrict__ b1, const float* __restrict__ W2,
                  const float* __restrict__ b2, const float* __restrict__ cb,
                  const float* __restrict__ cbnorm,
                  const int* __restrict__ cnt, const int* __restrict__ list,
                  float* __restrict__ outIdx)
{
    __shared__ float xr[1024];
    __shared__ float hr[512];
    __shared__ float er[256];
    __shared__ float dv[128];
    __shared__ int   di[128];

    const int tid = threadIdx.x;
    const int n = *cnt;
    for (int it = blockIdx.x; it < n; it += gridDim.x) {
        const int row = list[it];
        __syncthreads();   // LDS reuse guard across iterations
        #pragma unroll
        for (int i = 0; i < 4; ++i)
            xr[tid + i * 256] = x[(size_t)row * D_INK + tid + i * 256];
        __syncthreads();
        // h = relu(x_row @ W1 + b1): 2 cols/thread
        {
            const int c = tid * 2;
            float s0 = 0.f, s1 = 0.f;
            for (int k = 0; k < D_INK; ++k) {
                const float xv = xr[k];
                const float2 wv = *(const float2*)(W1 + (size_t)k * D_HID + c);
                s0 = fmaf(xv, wv.x, s0);
                s1 = fmaf(xv, wv.y, s1);
            }
            hr[c]     = fmaxf(s0 + b1[c], 0.f);
            hr[c + 1] = fmaxf(s1 + b1[c + 1], 0.f);
        }
        __syncthreads();
        // enc = h @ W2 + b2: 1 col/thread
        {
            float s = 0.f;
            for (int k = 0; k < D_HID; ++k)
                s = fmaf(hr[k], W2[(size_t)k * D_CODE_ + tid], s);
            er[tid] = s + b2[tid];
        }
        __syncthreads();
        // distances in reference expanded form: (e2 - 2*dot) + cbnorm
        if (tid < 128) {
            float e2 = 0.f;
            for (int k = 0; k < D_CODE_; ++k) e2 = fmaf(er[k], er[k], e2);
            float dot = 0.f;
            const float* cr = cb + (size_t)tid * D_CODE_;
            for (int k = 0; k < D_CODE_; ++k) dot = fmaf(er[k], cr[k], dot);
            dv[tid] = (e2 - 2.0f * dot) + cbnorm[tid];
            di[tid] = tid;
        }
        __syncthreads();
        for (int st = 64; st >= 1; st >>= 1) {
            if (tid < st) {
                const float a = dv[tid], b = dv[tid + st];
                const int  ib = di[tid + st];
                if (b < a || (b == a && ib < di[tid])) { dv[tid] = b; di[tid] = ib; }
            }
            __syncthreads();
        }
        if (tid == 0) outIdx[row] = (float)di[0];
    }
}

// ---------------------------------------------------------------------------
__global__ void finalize_kernel(const float* __restrict__ accum, float* __restrict__ out)
{
    const float inv = 1.0f / (32768.0f * 256.0f);
    const float loss = (accum[0] + accum[1]) * inv;   // commitment == codebook
    out[32768] = loss;
    out[32769] = loss;
    out[32770] = 1.25f * loss;
}

// ---------------------------------------------------------------------------
extern "C" void kernel_launch(void* const* d_in, const int* in_sizes, int n_in,
                              void* d_out, int out_size, void* d_ws, size_t ws_size,
                              hipStream_t stream)
{
    (void)in_sizes; (void)n_in; (void)out_size; (void)ws_size;

    const float* x  = (const float*)d_in[0];  // [32768,1024]
    const float* W1 = (const float*)d_in[1];  // [1024,512]
    const float* b1 = (const float*)d_in[2];  // [512]
    const float* W2 = (const float*)d_in[3];  // [512,256]
    const float* b2 = (const float*)d_in[4];  // [256]
    const float* cb = (const float*)d_in[5];  // [128,256]
    float* out = (float*)d_out;

    // workspace layout (bytes)
    char* ws = (char*)d_ws;
    __bf16* W1Thi = (__bf16*)(ws + 0);                    // 1 MB
    __bf16* W1Tlo = (__bf16*)(ws + 1048576);              // 1 MB
    __bf16* W2Thi = (__bf16*)(ws + 2097152);              // 256 KB
    __bf16* W2Tlo = (__bf16*)(ws + 2359296);              // 256 KB
    __bf16* h_hi  = (__bf16*)(ws + 4194304);              // 32 MB
    __bf16* h_lo  = (__bf16*)(ws + 37748736);             // 32 MB
    float*  enc   = (float* )(ws + 71303168);             // 32 MB
    float*  cbT   = (float* )(ws + 104857600);            // 128 KB
    float*  cbn   = (float* )(ws + 104988672);            // 512 B
    float*  accum = (float* )(ws + 104989184);            // 64 B
    int*    cnt   = (int*  )(ws + 104989248);             // 64 B
    int*    list  = (int*  )(ws + 104989312);             // 128 KB

    prep_cb_kernel<<<N_CODES_, 256, 0, stream>>>(cb, cbT, cbn, accum, cnt);
    splitT_kernel<<<dim3(D_INK, D_HID / 256), 256, 0, stream>>>(W1, W1Thi, W1Tlo, D_INK, D_HID);
    splitT_kernel<<<dim3(D_HID, D_CODE_ / 256), 256, 0, stream>>>(W2, W2Thi, W2Tlo, D_HID, D_CODE_);

    // h(hi/lo) = relu(x @ W1 + b1)   M=32768 K=1024 N=512
    mfma_gemm_kernel<false, true><<<dim3(M_ROWS / 128, D_HID / 128), 256, 0, stream>>>(
        x, nullptr, nullptr, W1Thi, W1Tlo, b1, nullptr, h_hi, h_lo, D_INK, D_HID);
    // enc = h @ W2 + b2              M=32768 K=512  N=256
    mfma_gemm_kernel<true, false><<<dim3(M_ROWS / 128, D_CODE_ / 128), 256, 0, stream>>>(
        nullptr, h_hi, h_lo, W2Thi, W2Tlo, b2, enc, nullptr, nullptr, D_HID, D_CODE_);

    dist_argmin_kernel<<<M_ROWS / 128, 256, 0, stream>>>(enc, cbT, cbn, out, accum, cnt, list);
    fixup_kernel<<<256, 256, 0, stream>>>(x, W1, b1, W2, b2, cb, cbn, cnt, list, out);
    finalize_kernel<<<1, 1, 0, stream>>>(accum, out);
}